// Round 1
// baseline (16789.763 us; speedup 1.0000x reference)
//
#include <hip/hip_runtime.h>

// ManualLSTM: B=32, S=2048, I=256, H=512. Persistent kernel, 64 WGs x 256 thr.
// Round-3: DATAFLOW-TAGGED publish — no flags, no fences, no store-ack.
//  * h is published as 32-bit words (tag<<16)|bf16(h). Consumers issue all h
//    loads speculatively at step start and spin on the tag of the loaded data
//    itself. Removes per step: producer s_waitcnt vmcnt(0) ack, flag store,
//    and the flag-poll round trip; ~0.5 GB of flag-poll fetch traffic gone.
//  * Protocol: producer of step t writes slot t&1 with tag (t+1); consumer of
//    step t reads slot (t+1)&1 expecting tag t. A WG publishes t+1 only after
//    consuming all tag-t words, which proves all WGs consumed h_{t-1} before
//    that slot is overwritten (same invariant the flags enforced). Tags are
//    checked on words .x/.z of each 16B chunk (8B producer stores are the
//    atomicity unit, same assumption as the old 8B atomic publish).
//  * W_hh fragments live in VGPRs (64/lane): zero LDS traffic on the
//    post-arrival critical path. W_ih stays in LDS (x-part is off-path,
//    runs during h flight). x_{t+1} prefetch+cvt overlaps the h-MFMA chain.
//  * Cell math over 128 threads (2 cells each), 8B sc0 sc1 tagged store.
//    ONE __syncthreads per step (gat WAR hazard is covered by the tag spin:
//    a wave's step-t+1 gat writes are gated on our own cell threads' step-t
//    publishes, which strictly follow their gat reads).

#define BB 32
#define SS 2048
#define II 256
#define HH 512
#define GG 64
#define NT 256
#define SLOT (BB * HH)   // 16384 words per h slot

typedef __bf16 bf16x8 __attribute__((ext_vector_type(8)));
typedef float f32x4 __attribute__((ext_vector_type(4)));
typedef unsigned u32x4 __attribute__((ext_vector_type(4)));
typedef unsigned u32x2 __attribute__((ext_vector_type(2)));

union BFU { __bf16 h; unsigned short u; };
union FRG { unsigned d[4]; bf16x8 b; };

__device__ __forceinline__ bf16x8 cvt8(float4 a, float4 b) {
  bf16x8 r;
  r[0] = (__bf16)a.x; r[1] = (__bf16)a.y; r[2] = (__bf16)a.z; r[3] = (__bf16)a.w;
  r[4] = (__bf16)b.x; r[5] = (__bf16)b.y; r[6] = (__bf16)b.z; r[7] = (__bf16)b.w;
  return r;
}

__global__ __launch_bounds__(256, 1) void lstm_init(
    const float* __restrict__ h0, unsigned* __restrict__ hw) {
  int i = blockIdx.x * 256 + threadIdx.x;   // 0..16383 = B*H
  BFU cv; cv.h = (__bf16)h0[i];
  hw[SLOT + i] = (unsigned)cv.u;   // slot 1: tag 0 | bf16(h0)  (t=0 reads this)
  hw[i] = 0xFFFF0000u;             // slot 0: sentinel tag (ws is re-poisoned)
}

__global__ __launch_bounds__(256, 1) void lstm_persistent(
    const float* __restrict__ x, const float* __restrict__ c0,
    const float* __restrict__ W_ih, const float* __restrict__ b_ih,
    const float* __restrict__ W_hh, float* __restrict__ out,
    unsigned* __restrict__ hw) {
  __shared__ __bf16 Wi[32][264];   // x-part weights (row pad: 528B, 16B-aligned)
  __shared__ float gat[32][41];    // gates tile; pad 41 -> <=2-way on cell reads

  const int g = blockIdx.x;
  const int tid = threadIdx.x;

  // ---- stage W_ih slice into LDS as bf16 (once) ----
  for (int i = tid; i < 32 * II; i += NT) {
    const int r = i >> 8, k = i & 255;
    const int grow = (r >> 3) * HH + g * 8 + (r & 7);
    Wi[r][k] = (__bf16)W_ih[(size_t)grow * II + k];
  }

  // ---- MFMA mapping (M=32 batches, N=32 local gate cols) ----
  const int wave = tid >> 6;
  const int lane = tid & 63;
  const int lm = lane & 15;
  const int lq = lane >> 4;
  const int mtile = wave & 1;
  const int ntile = wave >> 1;
  const int am = mtile * 16 + lm;   // A row (batch)
  const int bn = ntile * 16 + lm;   // B row (local gate col)

  // ---- W_hh fragments -> registers, bf16 (16 x bf16x8 = 64 VGPR/lane) ----
  const int growb = (bn >> 3) * HH + g * 8 + (bn & 7);
  const float* whr = W_hh + (size_t)growb * HH + lq * 8;
#define WLD(N) const bf16x8 wb##N = \
  cvt8(*(const float4*)(whr + N * 32), *(const float4*)(whr + N * 32 + 4));
  WLD(0)  WLD(1)  WLD(2)  WLD(3)  WLD(4)  WLD(5)  WLD(6)  WLD(7)
  WLD(8)  WLD(9)  WLD(10) WLD(11) WLD(12) WLD(13) WLD(14) WLD(15)
#undef WLD

  // ---- cell mapping: 128 threads x 2 cells ----
  const int eb = tid >> 2;              // batch (valid for tid<128)
  const int cp = (tid & 3) * 2;         // even h-col within this WG's 8
  const int colg = g * 8 + cp;
  float2 cc = make_float2(0.f, 0.f), hl = make_float2(0.f, 0.f);
  float2 bI = {}, bF = {}, bG = {}, bO = {};
  if (tid < 128) {
    bI = *(const float2*)(b_ih + 0 * HH + colg);
    bF = *(const float2*)(b_ih + 1 * HH + colg);
    bG = *(const float2*)(b_ih + 2 * HH + colg);
    bO = *(const float2*)(b_ih + 3 * HH + colg);
    cc = *(const float2*)(c0 + eb * HH + colg);
  }

  const float* xrow = x + (size_t)am * (SS * II);
  const unsigned* hbE = hw + SLOT + am * HH + lq * 8;  // even t: read slot 1
  const unsigned* hbO = hw + am * HH + lq * 8;         // odd  t: read slot 0
  unsigned* pbE = hw + eb * HH + colg;                 // even t: write slot 0
  unsigned* pbO = hw + SLOT + eb * HH + colg;          // odd  t: write slot 1

  // ---- x fragment prefetch for t=0 ----
  bf16x8 xf0, xf1, xf2, xf3, xf4, xf5, xf6, xf7;
#define XPF(T) { const float* xt_ = xrow + (size_t)(T) * II + lq * 8; \
  xf0 = cvt8(*(const float4*)(xt_ + 0),   *(const float4*)(xt_ + 4));   \
  xf1 = cvt8(*(const float4*)(xt_ + 32),  *(const float4*)(xt_ + 36));  \
  xf2 = cvt8(*(const float4*)(xt_ + 64),  *(const float4*)(xt_ + 68));  \
  xf3 = cvt8(*(const float4*)(xt_ + 96),  *(const float4*)(xt_ + 100)); \
  xf4 = cvt8(*(const float4*)(xt_ + 128), *(const float4*)(xt_ + 132)); \
  xf5 = cvt8(*(const float4*)(xt_ + 160), *(const float4*)(xt_ + 164)); \
  xf6 = cvt8(*(const float4*)(xt_ + 192), *(const float4*)(xt_ + 196)); \
  xf7 = cvt8(*(const float4*)(xt_ + 224), *(const float4*)(xt_ + 228)); }
  XPF(0)

  __syncthreads();

#define LDC(Q, OFF) asm volatile( \
  "global_load_dwordx4 %0, %1, off offset:" #OFF " sc0 sc1" \
  : "=v"(Q) : "v"(hb) : "memory");
#define LDALL() { \
  LDC(q0, 0)     LDC(q1, 16)    LDC(q2, 128)   LDC(q3, 144)  \
  LDC(q4, 256)   LDC(q5, 272)   LDC(q6, 384)   LDC(q7, 400)  \
  LDC(q8, 512)   LDC(q9, 528)   LDC(q10, 640)  LDC(q11, 656) \
  LDC(q12, 768)  LDC(q13, 784)  LDC(q14, 896)  LDC(q15, 912) \
  LDC(q16, 1024) LDC(q17, 1040) LDC(q18, 1152) LDC(q19, 1168) \
  LDC(q20, 1280) LDC(q21, 1296) LDC(q22, 1408) LDC(q23, 1424) \
  LDC(q24, 1536) LDC(q25, 1552) LDC(q26, 1664) LDC(q27, 1680) \
  LDC(q28, 1792) LDC(q29, 1808) LDC(q30, 1920) LDC(q31, 1936) }
#define CHK(Q) bad |= (Q.x ^ etag) | (Q.z ^ etag);
#define XMF(N) { const bf16x8 wib = *(const bf16x8*)(&Wi[bn][N * 32 + lq * 8]); \
  accA = __builtin_amdgcn_mfma_f32_16x16x32_bf16(xf##N, wib, accA, 0, 0, 0); }
#define HMF(QA, QB, WN, ACC) { FRG u_; \
  u_.d[0] = __builtin_amdgcn_perm(QA.y, QA.x, 0x05040100u); \
  u_.d[1] = __builtin_amdgcn_perm(QA.w, QA.z, 0x05040100u); \
  u_.d[2] = __builtin_amdgcn_perm(QB.y, QB.x, 0x05040100u); \
  u_.d[3] = __builtin_amdgcn_perm(QB.w, QB.z, 0x05040100u); \
  ACC = __builtin_amdgcn_mfma_f32_16x16x32_bf16(u_.b, WN, ACC, 0, 0, 0); }

  for (int t = 0; t < SS; ++t) {
    const unsigned etag = ((unsigned)t) << 16;
    const unsigned* hb = (t & 1) ? hbO : hbE;
    u32x4 q0, q1, q2, q3, q4, q5, q6, q7, q8, q9, q10, q11, q12, q13, q14, q15,
          q16, q17, q18, q19, q20, q21, q22, q23, q24, q25, q26, q27, q28, q29,
          q30, q31;

    // ---- 1. speculative h loads: issued first, fly during the x-part ----
    LDALL();

    // ---- 2. x-part: LDS + register operands only, no global waits ----
    f32x4 accA = {0.f, 0.f, 0.f, 0.f};
    f32x4 accB = {0.f, 0.f, 0.f, 0.f};
    XMF(0) XMF(1) XMF(2) XMF(3) XMF(4) XMF(5) XMF(6) XMF(7)

    // ---- 3. spin on the data's own tags (no flags anywhere) ----
    for (;;) {
      asm volatile("s_waitcnt vmcnt(0)" ::: "memory");
      __builtin_amdgcn_sched_barrier(0);
      unsigned bad = 0u;
      CHK(q0)  CHK(q1)  CHK(q2)  CHK(q3)  CHK(q4)  CHK(q5)  CHK(q6)  CHK(q7)
      CHK(q8)  CHK(q9)  CHK(q10) CHK(q11) CHK(q12) CHK(q13) CHK(q14) CHK(q15)
      CHK(q16) CHK(q17) CHK(q18) CHK(q19) CHK(q20) CHK(q21) CHK(q22) CHK(q23)
      CHK(q24) CHK(q25) CHK(q26) CHK(q27) CHK(q28) CHK(q29) CHK(q30) CHK(q31)
      if (__all((int)((bad & 0xffff0000u) == 0u))) break;
      LDALL();
    }

    // ---- 4. x prefetch for t+1: latency hides under the h-MFMA chain ----
    { const int tn = (t < SS - 1) ? t + 1 : t; XPF(tn) }

    // ---- 5. h-part: extract (v_perm) + MFMA, two independent acc chains ----
    HMF(q0, q1, wb0, accB)    HMF(q2, q3, wb1, accA)
    HMF(q4, q5, wb2, accB)    HMF(q6, q7, wb3, accA)
    HMF(q8, q9, wb4, accB)    HMF(q10, q11, wb5, accA)
    HMF(q12, q13, wb6, accB)  HMF(q14, q15, wb7, accA)
    HMF(q16, q17, wb8, accB)  HMF(q18, q19, wb9, accA)
    HMF(q20, q21, wb10, accB) HMF(q22, q23, wb11, accA)
    HMF(q24, q25, wb12, accB) HMF(q26, q27, wb13, accA)
    HMF(q28, q29, wb14, accB) HMF(q30, q31, wb15, accA)

    // D layout: col = lane&15, row = (lane>>4)*4 + r (m89-verified)
#pragma unroll
    for (int r = 0; r < 4; ++r)
      gat[mtile * 16 + lq * 4 + r][ntile * 16 + lm] = accA[r] + accB[r];
    __syncthreads();

    // ---- 6. cell math (128 threads x 2 cells) + tagged 8B publish ----
    if (tid < 128) {
      float hv0, hv1;
      unsigned pw0, pw1;
      const unsigned th = ((unsigned)(t + 1)) << 16;
      {
        float iv = gat[eb][cp]      + bI.x;
        float fv = gat[eb][8 + cp]  + bF.x;
        float gv = gat[eb][16 + cp] + bG.x;
        float o  = gat[eb][24 + cp] + bO.x;
        iv = 1.f / (1.f + __expf(-iv));
        fv = 1.f / (1.f + __expf(-fv));
        o  = 1.f / (1.f + __expf(-o));
        gv = 2.f / (1.f + __expf(-2.f * gv)) - 1.f;
        cc.x = fv * cc.x + iv * gv;
        const float thh = 2.f / (1.f + __expf(-2.f * cc.x)) - 1.f;
        hv0 = o * thh;
        BFU b_; b_.h = (__bf16)hv0;
        pw0 = th | (unsigned)b_.u;
      }
      {
        float iv = gat[eb][cp + 1]      + bI.y;
        float fv = gat[eb][8 + cp + 1]  + bF.y;
        float gv = gat[eb][16 + cp + 1] + bG.y;
        float o  = gat[eb][24 + cp + 1] + bO.y;
        iv = 1.f / (1.f + __expf(-iv));
        fv = 1.f / (1.f + __expf(-fv));
        o  = 1.f / (1.f + __expf(-o));
        gv = 2.f / (1.f + __expf(-2.f * gv)) - 1.f;
        cc.y = fv * cc.y + iv * gv;
        const float thh = 2.f / (1.f + __expf(-2.f * cc.y)) - 1.f;
        hv1 = o * thh;
        BFU b_; b_.h = (__bf16)hv1;
        pw1 = th | (unsigned)b_.u;
      }
      hl.x = hv0; hl.y = hv1;
      u32x2 pv; pv.x = pw0; pv.y = pw1;
      unsigned* pb = (t & 1) ? pbO : pbE;
      asm volatile("global_store_dwordx2 %0, %1, off sc0 sc1"
                   :: "v"(pb), "v"(pv) : "memory");
      // out[] store after publish: off the critical path, plain cached store
      float2 ov; ov.x = hv0; ov.y = hv1;
      *(float2*)(out + (size_t)eb * (SS * HH) + (size_t)t * HH + colg) = ov;
    }
  }

  // ---- final h, c ----
  if (tid < 128) {
    const size_t OUTH = (size_t)BB * SS * HH;
    *(float2*)(out + OUTH + eb * HH + colg) = hl;
    *(float2*)(out + OUTH + BB * HH + eb * HH + colg) = cc;
  }
}

extern "C" void kernel_launch(void* const* d_in, const int* in_sizes, int n_in,
                              void* d_out, int out_size, void* d_ws, size_t ws_size,
                              hipStream_t stream) {
  const float* x    = (const float*)d_in[0];
  const float* h0   = (const float*)d_in[1];
  const float* c0   = (const float*)d_in[2];
  const float* W_ih = (const float*)d_in[3];
  const float* b_ih = (const float*)d_in[4];
  const float* W_hh = (const float*)d_in[5];
  float* out = (float*)d_out;

  // ws layout: tagged h words, 2 slots x 32x512 u32 = 128KB. No flags.
  unsigned* hw = (unsigned*)d_ws;

  lstm_init<<<64, 256, 0, stream>>>(h0, hw);
  lstm_persistent<<<GG, 256, 0, stream>>>(x, c0, W_ih, b_ih, W_hh, out, hw);
}